// Round 2
// baseline (131.903 us; speedup 1.0000x reference)
//
#include <hip/hip_runtime.h>

#define BATCH 8
#define HDIM  512
#define WDIM  512
#define PLANE (HDIM * WDIM)

// Gather quadrant invariant: ix = i*256/511 + 255.5 + 256*sigmoid > 255.5, same for iy.
// => x0,y0 >= 255 always. Pack only x in [254,512], y in [254,512].
//
// v11 pack layout (per image): two parity packs (p = x0 & 1).
//   pack[p][Qc][y - 254][s]  where texel column = 254 + 2*Qc + p + s, s in {0,1}
//   8 bytes per texel (c0,c1,c2,pad as half4), 16 B per (Qc,y).
// A bilinear quad (x0..x0+1, y0..y0+1) = contiguous 32 B at 16 B alignment.
#define QC_N      129
#define YROW0     254
#define YROWS     259                   // rows 254..512 (row 512 = zeros)
#define YSTRIDE   260
#define QSTRIDE   (YSTRIDE * 16)        // 4160 B per Q  (= (Qc<<12)+(Qc<<6))
#define PARSTRIDE (QC_N * QSTRIDE)      // 536640 B per parity
#define IMGSTRIDE (2 * PARSTRIDE)       // 1073280 B per image

typedef _Float16 half2v __attribute__((ext_vector_type(2)));
typedef _Float16 half8v __attribute__((ext_vector_type(8)));
typedef float    f2v    __attribute__((ext_vector_type(2)));

// one 16B pack entry: texel s=0 (c0,c1),(c2,0) then texel s=1 (c0,c1),(c2,0)
struct __align__(16) HQuad { half2v p0, p1, p2, p3; };

#if __has_builtin(__builtin_amdgcn_fdot2)
#define FDOT2(a, b, c) __builtin_amdgcn_fdot2((a), (b), (c), false)
#else
#define FDOT2(a, b, c) fmaf((float)(a).x, (float)(b).x, fmaf((float)(a).y, (float)(b).y, (c)))
#endif

#if __has_builtin(__builtin_amdgcn_exp2f)
#define EXP2F(x) __builtin_amdgcn_exp2f(x)
#else
#define EXP2F(x) exp2f(x)
#endif

// ---------- repack into quad-contiguous parity tiles ----------
// grid = 8 * 2 * QC_N blocks; block (b, p, Qc) writes rows 254..512 of one x-pair.
__global__ __launch_bounds__(256) void repack_tiles(
    const float* __restrict__ x,   // [B,3,H,W]
    char* __restrict__ xp)
{
    int b    = blockIdx.x & 7;                 // image -> XCD locality
    int rest = blockIdx.x >> 3;
    int p    = rest & 1;
    int Qc   = rest >> 1;                      // 0..128
    int xb0  = 254 + 2 * Qc + p;               // first texel column (<= 511)
    int x1   = xb0 + 1;                        // may be 512 (zero-fill)
    bool x1v = (x1 < 512);                     // block-uniform

    const float* xb = x + (size_t)b * 3 * PLANE;
    char* dst = xp + (size_t)b * IMGSTRIDE + (size_t)p * PARSTRIDE
                   + (size_t)Qc * QSTRIDE;

    for (int t = threadIdx.x; t < YROWS; t += 256) {
        int y = YROW0 + t;
        half8v o;
        if (y < 512) {
            int base = (y << 9) + xb0;
            float a0 = xb[base];
            float a1 = xb[PLANE + base];
            float a2 = xb[2 * PLANE + base];
            float b0 = 0.f, b1c = 0.f, b2c = 0.f;
            if (x1v) {
                b0  = xb[base + 1];
                b1c = xb[PLANE + base + 1];
                b2c = xb[2 * PLANE + base + 1];
            }
            o[0] = (_Float16)a0; o[1] = (_Float16)a1; o[2] = (_Float16)a2; o[3] = (_Float16)0.f;
            o[4] = (_Float16)b0; o[5] = (_Float16)b1c; o[6] = (_Float16)b2c; o[7] = (_Float16)0.f;
        } else {
#pragma unroll
            for (int k = 0; k < 8; k++) o[k] = (_Float16)0.f;
        }
        *(half8v*)(dst + (size_t)t * 16) = o;
    }
}

// ---------- main v11: 2 px/thread; quad-contiguous gathers ----------
// grid = 8 images * 512 rows; thread t handles pixels (i, 2t) and (i, 2t+1)
__global__ __launch_bounds__(256) void seesaw_v11(
    const float* __restrict__ x,     // [B,3,H,W] fp32 (conv + mirror)
    const char* __restrict__ xpack,  // parity tile packs
    const float* __restrict__ w1, const float* __restrict__ b1,
    const float* __restrict__ w2, const float* __restrict__ b2,
    float* __restrict__ out)
{
    int t  = threadIdx.x;
    int b  = blockIdx.x & 7;          // image -> XCD locality
    int i  = blockIdx.x >> 3;         // SCALAR row (block covers a full row)
    int j0 = t << 1;                  // even col; px0 = j0, px1 = j0+1

    const float* xb = x + (size_t)b * 3 * PLANE;
    const char*  hb = xpack + (size_t)b * IMGSTRIDE;

    // ---- conv inputs for the pixel pair: per rowchan cols {j0-1, j0, j0+1, j0+2} ----
    int cm = j0 - 1; if (cm < 0) cm = 0;
    int cp = j0 + 2; if (cp > 511) cp = 511;
    bool jlo = (t == 0), jhi = (t == 255);

    float vm[9], va[9], vb9[9], vp9[9];   // index r = c*3 + di
    if (i >= 1 && i <= 510) {             // interior rows (uniform branch)
#pragma unroll
        for (int di = 0; di < 3; di++) {
            const float* row = xb + ((i + di - 1) << 9);
#pragma unroll
            for (int c = 0; c < 3; c++) {
                const float* rc = row + c * PLANE;
                float m = rc[cm]; if (jlo) m = 0.f;
                f2v  mid = *(const f2v*)(rc + j0);     // 8B aligned (j0 even)
                float pv = rc[cp]; if (jhi) pv = 0.f;
                int r = c * 3 + di;
                vm[r] = m; va[r] = mid[0]; vb9[r] = mid[1]; vp9[r] = pv;
            }
        }
    } else {                               // y-edge rows (16/4096 blocks)
#pragma unroll
        for (int di = 0; di < 3; di++) {
            int y = i + di - 1;
            bool yv = (unsigned)y < (unsigned)HDIM;
            const float* row = xb + ((yv ? y : 0) << 9);
#pragma unroll
            for (int c = 0; c < 3; c++) {
                const float* rc = row + c * PLANE;
                float m = rc[cm]; if (jlo || !yv) m = 0.f;
                f2v  mid = *(const f2v*)(rc + j0);
                float pv = rc[cp]; if (jhi || !yv) pv = 0.f;
                float m0 = yv ? mid[0] : 0.f;
                float m1 = yv ? mid[1] : 0.f;
                int r = c * 3 + di;
                vm[r] = m; va[r] = m0; vb9[r] = m1; vp9[r] = pv;
            }
        }
    }
    __builtin_amdgcn_sched_barrier(0);   // all 27 conv loads issued before math

    // ---- build tap arrays (register renames) ----
    float tap0[27], tap1[27];   // k = c*9 + di*3 + dj
#pragma unroll
    for (int c = 0; c < 3; c++)
#pragma unroll
        for (int di = 0; di < 3; di++) {
            int r = c * 3 + di, k = c * 9 + di * 3;
            tap0[k]     = vm[r];  tap0[k + 1] = va[r];  tap0[k + 2] = vb9[r];
            tap1[k]     = va[r];  tap1[k + 1] = vb9[r]; tap1[k + 2] = vp9[r];
        }

    // ---- 27-tap dot via packed f32 FMA + sigmoid (pre-scaled by 256) ----
    const float NLOG2E = -1.44269504f;
    auto conv8 = [&](const float* tap, float* s2) {
        f2v V[13];
#pragma unroll
        for (int k = 0; k < 13; k++) { V[k][0] = tap[2 * k]; V[k][1] = tap[2 * k + 1]; }
#pragma unroll
        for (int e = 0; e < 8; e++) {
            const float* we = w1 + e * 27;
            f2v a2; a2[0] = b1[e]; a2[1] = 0.f;
#pragma unroll
            for (int k = 0; k < 13; k++) {
                f2v ww; ww[0] = we[2 * k]; ww[1] = we[2 * k + 1];
                a2 = __builtin_elementwise_fma(V[k], ww, a2);
            }
            float acc = a2[0] + a2[1] + tap[26] * we[26];
            s2[e] = 256.0f * __builtin_amdgcn_rcpf(1.0f + EXP2F(acc * NLOG2E));
        }
    };
    float s0[8], s1[8];
    conv8(tap0, s0);
    conv8(tap1, s1);

    // ---- w2 rows packed to half2 (wave-uniform) ----
    half2v w2a[5], w2b[5];
#pragma unroll
    for (int q = 0; q < 5; q++) {
        w2a[q][0] = (_Float16)w2[q * 3];
        w2a[q][1] = (_Float16)w2[q * 3 + 1];
        w2b[q][0] = (_Float16)w2[q * 3 + 2];
        w2b[q][1] = (_Float16)0.f;
    }

    const float k511 = 256.0f / 511.0f;
    float fxb = fmaf((float)i, k511, 255.5f);   // feeds gx (reference axis swap)
    float fy0 = fmaf((float)j0, k511, 255.5f);
    float fy1 = fy0 + k511;

    // ---- gather phase 1: quad base addresses + weights ----
    int   adrA[5], adrB[5];
    float wXA[5][2], wYA[5][2], wXB[5][2], wYB[5][2];
    auto phase1 = [&](const float* s2, float fyb, int (&adr)[5],
                      float (&wX)[5][2], float (&wY)[5][2]) {
#pragma unroll
        for (int q = 0; q < 5; q++) {
            float ixf = (q < 4) ? (fxb + s2[2 * q])     : fxb;
            float iyf = (q < 4) ? (fyb + s2[2 * q + 1]) : fyb;
            int ix0 = (int)ixf, iy0 = (int)iyf;         // positive: trunc == floor; >= 255
            float wx1 = ixf - (float)ix0, wy1 = iyf - (float)iy0;
            wX[q][0] = (ix0 <= 511) ? (1.f - wx1) : 0.f;
            wX[q][1] = (ix0 <= 510) ? wx1 : 0.f;
            wY[q][0] = (iy0 <= 511) ? (1.f - wy1) : 0.f;
            wY[q][1] = (iy0 <= 510) ? wy1 : 0.f;
            int x0c = min(ix0, 511);
            int y0c = min(iy0, 511);
            int Qc  = (x0c >> 1) - 127;                 // 0..128
            int off = (Qc << 12) + (Qc << 6) + ((y0c - 254) << 4);
            adr[q] = off + ((x0c & 1) ? PARSTRIDE : 0);
            // rows y0c,y0c+1 and cols x0c,x0c+1 always inside the written pack
            // (row 512 / col 512 slots are zero-filled; their weights are 0).
        }
    };

    // ---- gather phase 2: all 20 quad-row loads back-to-back ----
    phase1(s0, fy0, adrA, wXA, wYA);
    HQuad qA[5][2];
#pragma unroll
    for (int q = 0; q < 5; q++) {
        qA[q][0] = *(const HQuad*)(hb + (size_t)adrA[q]);        // row y0: (x0,x0+1)
        qA[q][1] = *(const HQuad*)(hb + (size_t)adrA[q] + 16);   // row y0+1
    }
    phase1(s1, fy1, adrB, wXB, wYB);   // VALU overlaps px0 loads
    HQuad qB[5][2];
#pragma unroll
    for (int q = 0; q < 5; q++) {
        qB[q][0] = *(const HQuad*)(hb + (size_t)adrB[q]);
        qB[q][1] = *(const HQuad*)(hb + (size_t)adrB[q] + 16);
    }
    __builtin_amdgcn_sched_barrier(0);   // pin all 20 gathers in flight before any use

    // ---- gather phase 3: fp16 dot per texel, bilinear combine ----
    float ogA[3] = {0.f, 0.f, 0.f}, ogB[3] = {0.f, 0.f, 0.f};
    auto phase3 = [&](HQuad (&qv)[5][2], float (&wX)[5][2], float (&wY)[5][2], float* og) {
#pragma unroll
        for (int q = 0; q < 5; q++) {
            int g = q / 3;              // 0,0,0,1,1
            float dl0 = FDOT2(qv[q][0].p0, w2a[q], FDOT2(qv[q][0].p1, w2b[q], 0.f));
            float dh0 = FDOT2(qv[q][0].p2, w2a[q], FDOT2(qv[q][0].p3, w2b[q], 0.f));
            float dl1 = FDOT2(qv[q][1].p0, w2a[q], FDOT2(qv[q][1].p1, w2b[q], 0.f));
            float dh1 = FDOT2(qv[q][1].p2, w2a[q], FDOT2(qv[q][1].p3, w2b[q], 0.f));
            float r0 = fmaf(dh0, wX[q][1], dl0 * wX[q][0]);
            float r1 = fmaf(dh1, wX[q][1], dl1 * wX[q][0]);
            og[g] = fmaf(r1, wY[q][1], fmaf(r0, wY[q][0], og[g]));
        }
    };
    phase3(qA, wXA, wYA, ogA);
    phase3(qB, wXB, wYB, ogB);

    // ---- mirror points p=5..8: only pixel (0,0) of each image contributes ----
    if ((i | j0) == 0) {
#pragma unroll
        for (int p = 5; p < 9; p++) {
            float ixf = fxb + 512.0f - s0[2 * (p - 5)];
            float iyf = fy0 + 512.0f - s0[2 * (p - 5) + 1];
            float ix0f = floorf(ixf), iy0f = floorf(iyf);
            float wx1 = ixf - ix0f, wy1 = iyf - iy0f;
            float wx0 = 1.f - wx1,  wy0 = 1.f - wy1;
            int ix0 = (int)ix0f, iy0 = (int)iy0f;
            float t0 = 0.f, t1 = 0.f, t2 = 0.f;
            for (int cy = 0; cy < 2; cy++) {
                int yc2 = iy0 + cy;
                if (yc2 < 0 || yc2 >= HDIM) continue;
                float wy = cy ? wy1 : wy0;
                for (int cx = 0; cx < 2; cx++) {
                    int xcc2 = ix0 + cx;
                    if (xcc2 < 0 || xcc2 >= WDIM) continue;
                    float wgt = wy * (cx ? wx1 : wx0);
                    int base = (yc2 << 9) + xcc2;
                    t0 = fmaf(xb[base],             wgt, t0);
                    t1 = fmaf(xb[PLANE + base],     wgt, t1);
                    t2 = fmaf(xb[2 * PLANE + base], wgt, t2);
                }
            }
            int g  = p / 3;
            int k0 = (p % 3) * 3;
            ogA[g] = fmaf(t0, w2[g * 9 + k0 + 0], ogA[g]);
            ogA[g] = fmaf(t1, w2[g * 9 + k0 + 1], ogA[g]);
            ogA[g] = fmaf(t2, w2[g * 9 + k0 + 2], ogA[g]);
        }
    }

    // ---- bias + relu + paired store ----
    size_t ob = (size_t)(b * 3) * PLANE + ((size_t)i << 9) + j0;
#pragma unroll
    for (int g = 0; g < 3; g++) {
        float u0 = ogA[g] + b2[g];
        float u1 = ogB[g] + b2[g];
        f2v st;
        st[0] = u0 > 0.f ? u0 : 0.f;
        st[1] = u1 > 0.f ? u1 : 0.f;
        *(f2v*)(out + ob + (size_t)g * PLANE) = st;
    }
}

// ---------- no-workspace fallback (round-1 style) ----------
__global__ __launch_bounds__(256) void seesaw_fused_v1(
    const float* __restrict__ x, const float* __restrict__ w1,
    const float* __restrict__ b1, const float* __restrict__ w2,
    const float* __restrict__ b2, float* __restrict__ out)
{
    int t = threadIdx.x;
    int gid = blockIdx.x * 256 + t;
    int j = gid & (WDIM - 1);
    int i = (gid >> 9) & (HDIM - 1);
    int b = gid >> 18;
    const float* xb = x + (size_t)b * 3 * PLANE;
    float acc[8];
#pragma unroll
    for (int e = 0; e < 8; e++) acc[e] = b1[e];
#pragma unroll
    for (int di = 0; di < 3; di++) {
        int y = i + di - 1;
        if (y < 0 || y >= HDIM) continue;
#pragma unroll
        for (int dj = 0; dj < 3; dj++) {
            int xc = j + dj - 1;
            if (xc < 0 || xc >= WDIM) continue;
            size_t base = (size_t)y * WDIM + xc;
#pragma unroll
            for (int c = 0; c < 3; c++) {
                float v = xb[(size_t)c * PLANE + base];
#pragma unroll
                for (int e = 0; e < 8; e++)
                    acc[e] = fmaf(v, w1[e * 27 + c * 9 + di * 3 + dj], acc[e]);
            }
        }
    }
    float s[8];
#pragma unroll
    for (int e = 0; e < 8; e++) s[e] = 1.0f / (1.0f + __expf(-acc[e]));
    const float inv511 = 1.0f / 511.0f;
    float bx = (float)i * inv511, by = (float)j * inv511;
    float og0 = 0.f, og1 = 0.f, og2 = 0.f;
#pragma unroll
    for (int p = 0; p < 9; p++) {
        float c0, c1;
        if (p < 4)       { c0 = s[2 * p];              c1 = s[2 * p + 1]; }
        else if (p == 4) { c0 = 0.f;                   c1 = 0.f; }
        else             { c0 = 2.0f - s[2 * (p - 5)]; c1 = 2.0f - s[2 * (p - 5) + 1]; }
        float ixf = (bx + c0) * 256.0f + 255.5f;
        float iyf = (by + c1) * 256.0f + 255.5f;
        float ix0f = floorf(ixf), iy0f = floorf(iyf);
        float wx1 = ixf - ix0f, wy1 = iyf - iy0f;
        float wx0 = 1.f - wx1,  wy0 = 1.f - wy1;
        int ix0 = (int)ix0f, iy0 = (int)iy0f;
        float s0 = 0.f, s1 = 0.f, s2 = 0.f;
#pragma unroll
        for (int cy = 0; cy < 2; cy++) {
            int yc = iy0 + cy;
            if (yc < 0 || yc >= HDIM) continue;
            float wy = cy ? wy1 : wy0;
#pragma unroll
            for (int cx = 0; cx < 2; cx++) {
                int xcc = ix0 + cx;
                if (xcc < 0 || xcc >= WDIM) continue;
                float wgt = wy * (cx ? wx1 : wx0);
                size_t base = (size_t)yc * WDIM + xcc;
                s0 = fmaf(xb[base],             wgt, s0);
                s1 = fmaf(xb[PLANE + base],     wgt, s1);
                s2 = fmaf(xb[2 * PLANE + base], wgt, s2);
            }
        }
        int g  = p / 3;
        int k0 = (p % 3) * 3;
        float* og = (g == 0) ? &og0 : (g == 1) ? &og1 : &og2;
        *og = fmaf(s0, w2[g * 9 + k0 + 0], *og);
        *og = fmaf(s1, w2[g * 9 + k0 + 1], *og);
        *og = fmaf(s2, w2[g * 9 + k0 + 2], *og);
    }
    size_t ob = (size_t)(b * 3) * PLANE + (size_t)i * WDIM + j;
    float v0 = og0 + b2[0], v1 = og1 + b2[1], v2 = og2 + b2[2];
    out[ob]             = v0 > 0.f ? v0 : 0.f;
    out[ob + PLANE]     = v1 > 0.f ? v1 : 0.f;
    out[ob + 2 * PLANE] = v2 > 0.f ? v2 : 0.f;
}

extern "C" void kernel_launch(void* const* d_in, const int* in_sizes, int n_in,
                              void* d_out, int out_size, void* d_ws, size_t ws_size,
                              hipStream_t stream) {
    const float* x  = (const float*)d_in[0];
    const float* w1 = (const float*)d_in[1];
    const float* b1 = (const float*)d_in[2];
    const float* w2 = (const float*)d_in[3];
    const float* b2 = (const float*)d_in[4];
    float* out = (float*)d_out;

    int total = BATCH * HDIM * WDIM;                 // 2,097,152
    size_t need = (size_t)BATCH * IMGSTRIDE + 16;    // ~8.2 MiB parity tile packs

    if (ws_size >= need) {
        repack_tiles<<<8 * 2 * QC_N, 256, 0, stream>>>(x, (char*)d_ws);
        seesaw_v11<<<BATCH * HDIM, 256, 0, stream>>>(x, (const char*)d_ws,
                                                     w1, b1, w2, b2, out);
    } else {
        seesaw_fused_v1<<<total / 256, 256, 0, stream>>>(x, w1, b1, w2, b2, out);
    }
}

// Round 3
// 120.538 us; speedup vs baseline: 1.0943x; 1.0943x over previous
//
#include <hip/hip_runtime.h>

#define BATCH 8
#define HDIM  512
#define WDIM  512
#define PLANE (HDIM * WDIM)

// Gather quadrant invariant: ix = i*256/511 + 255.5 + 256*sigmoid > 255.5, same for iy.
// => x0,y0 >= 255 always; clamped x0c,y0c in [255,511], corners reach 512 (zero).
//
// v12 pack: per gather-point q (0..4), per (y-parity, x-parity), per quad (Qy,Qx):
//   4 fp16 scalars = dot(rgb(corner), w2[3q:3q+3]) for corners
//   (X0,Y0),(X0+1,Y0),(X0,Y0+1),(X0+1,Y0+1), X0 = 2*Qx+254+px, Y0 = 2*Qy+254+py.
// One bilinear quad for one point = ONE 8-byte load.
#define QN      129
#define QPAIRS  (QN * QN)               // 16641 quads per parity
#define QPLANE  (4 * QPAIRS * 8)        // 532512 B per q (4 parities)
#define IMG12   (5 * QPLANE)            // 2662560 B per image

// ---- legacy v11 pack constants (tier-2 fallback) ----
#define QC_N      129
#define YROW0     254
#define YROWS     259
#define YSTRIDE   260
#define QSTRIDE   (YSTRIDE * 16)
#define PARSTRIDE (QC_N * QSTRIDE)
#define IMGSTRIDE (2 * PARSTRIDE)

typedef _Float16 half2v __attribute__((ext_vector_type(2)));
typedef _Float16 half4v __attribute__((ext_vector_type(4)));
typedef _Float16 half8v __attribute__((ext_vector_type(8)));
typedef float    f2v    __attribute__((ext_vector_type(2)));

struct __align__(16) HQuad { half2v p0, p1, p2, p3; };   // v11 entry
struct __align__(8)  HPair { half2v lo, hi; };           // v12 entry: row y0, row y0+1

#if __has_builtin(__builtin_amdgcn_fdot2)
#define FDOT2(a, b, c) __builtin_amdgcn_fdot2((a), (b), (c), false)
#else
#define FDOT2(a, b, c) fmaf((float)(a).x, (float)(b).x, fmaf((float)(a).y, (float)(b).y, (c)))
#endif

#if __has_builtin(__builtin_amdgcn_exp2f)
#define EXP2F(x) __builtin_amdgcn_exp2f(x)
#else
#define EXP2F(x) exp2f(x)
#endif

// ---------- v12 repack: per-quad pre-dotted fp16 scalars ----------
// grid = 129(Qy) * 4(P) * 8(b); threads 0..128 = Qx.
__global__ __launch_bounds__(256) void repack_dots(
    const float* __restrict__ x,    // [B,3,H,W]
    const float* __restrict__ w2,   // [3][9] flat; point q uses w2[3q..3q+2]
    char* __restrict__ xp)
{
    int b  = blockIdx.x & 7;                  // image -> XCD locality
    int P  = (blockIdx.x >> 3) & 3;           // py*2+px
    int Qy = blockIdx.x >> 5;                 // 0..128
    int Qx = threadIdx.x;
    if (Qx >= QN) return;
    int px = P & 1, py = P >> 1;
    int X0 = 2 * Qx + 254 + px;               // 254..511
    int Y0 = 2 * Qy + 254 + py;

    const float* xb = x + (size_t)b * 3 * PLANE;

    float vc[4][3];
#pragma unroll
    for (int cy = 0; cy < 2; cy++)
#pragma unroll
        for (int cx = 0; cx < 2; cx++) {
            int xx = X0 + cx, yy = Y0 + cy;          // up to 512
            bool vld = (xx <= 511) && (yy <= 511);
            int xs = min(xx, 511), ys = min(yy, 511);
            int base = (ys << 9) + xs;
            int ci = cy * 2 + cx;
            vc[ci][0] = vld ? xb[base]             : 0.f;
            vc[ci][1] = vld ? xb[PLANE + base]     : 0.f;
            vc[ci][2] = vld ? xb[2 * PLANE + base] : 0.f;
        }

    char* dst = xp + (size_t)b * IMG12 + (size_t)((P * QPAIRS + Qy * QN + Qx) << 3);
#pragma unroll
    for (int q = 0; q < 5; q++) {
        float wa = w2[3 * q], wb = w2[3 * q + 1], wc = w2[3 * q + 2];
        half4v o;
#pragma unroll
        for (int ci = 0; ci < 4; ci++) {
            float v = fmaf(vc[ci][2], wc, fmaf(vc[ci][1], wb, vc[ci][0] * wa));
            o[ci] = (_Float16)v;
        }
        *(half4v*)(dst + q * QPLANE) = o;
    }
}

// ---------- main v12: 2 px/thread; one 8-B load per gather point ----------
// grid = 8 images * 512 rows; thread t handles pixels (i, 2t) and (i, 2t+1)
__global__ __launch_bounds__(256) void seesaw_v12(
    const float* __restrict__ x,     // [B,3,H,W] fp32 (conv + mirror)
    const char* __restrict__ xpack,  // v12 dot packs
    const float* __restrict__ w1, const float* __restrict__ b1,
    const float* __restrict__ w2, const float* __restrict__ b2,
    float* __restrict__ out)
{
    int t  = threadIdx.x;
    int b  = blockIdx.x & 7;          // image -> XCD locality
    int i  = blockIdx.x >> 3;         // SCALAR row (block covers a full row)
    int j0 = t << 1;                  // even col; px0 = j0, px1 = j0+1

    const float* xb = x + (size_t)b * 3 * PLANE;
    const char*  hb = xpack + (size_t)b * IMG12;

    // ---- conv inputs for the pixel pair: per rowchan cols {j0-1, j0, j0+1, j0+2} ----
    int cm = j0 - 1; if (cm < 0) cm = 0;
    int cp = j0 + 2; if (cp > 511) cp = 511;
    bool jlo = (t == 0), jhi = (t == 255);

    float vm[9], va[9], vb9[9], vp9[9];   // index r = c*3 + di
    if (i >= 1 && i <= 510) {             // interior rows (uniform branch)
#pragma unroll
        for (int di = 0; di < 3; di++) {
            const float* row = xb + ((i + di - 1) << 9);
#pragma unroll
            for (int c = 0; c < 3; c++) {
                const float* rc = row + c * PLANE;
                float m = rc[cm]; if (jlo) m = 0.f;
                f2v  mid = *(const f2v*)(rc + j0);     // 8B aligned (j0 even)
                float pv = rc[cp]; if (jhi) pv = 0.f;
                int r = c * 3 + di;
                vm[r] = m; va[r] = mid[0]; vb9[r] = mid[1]; vp9[r] = pv;
            }
        }
    } else {                               // y-edge rows (16/4096 blocks)
#pragma unroll
        for (int di = 0; di < 3; di++) {
            int y = i + di - 1;
            bool yv = (unsigned)y < (unsigned)HDIM;
            const float* row = xb + ((yv ? y : 0) << 9);
#pragma unroll
            for (int c = 0; c < 3; c++) {
                const float* rc = row + c * PLANE;
                float m = rc[cm]; if (jlo || !yv) m = 0.f;
                f2v  mid = *(const f2v*)(rc + j0);
                float pv = rc[cp]; if (jhi || !yv) pv = 0.f;
                float m0 = yv ? mid[0] : 0.f;
                float m1 = yv ? mid[1] : 0.f;
                int r = c * 3 + di;
                vm[r] = m; va[r] = m0; vb9[r] = m1; vp9[r] = pv;
            }
        }
    }
    __builtin_amdgcn_sched_barrier(0);   // all 27 conv loads issued before math

    // ---- build tap arrays (register renames) ----
    float tap0[27], tap1[27];   // k = c*9 + di*3 + dj
#pragma unroll
    for (int c = 0; c < 3; c++)
#pragma unroll
        for (int di = 0; di < 3; di++) {
            int r = c * 3 + di, k = c * 9 + di * 3;
            tap0[k]     = vm[r];  tap0[k + 1] = va[r];  tap0[k + 2] = vb9[r];
            tap1[k]     = va[r];  tap1[k + 1] = vb9[r]; tap1[k + 2] = vp9[r];
        }

    // ---- 27-tap dot via packed f32 FMA + sigmoid (pre-scaled by 256) ----
    const float NLOG2E = -1.44269504f;
    auto conv8 = [&](const float* tap, float* s2) {
        f2v V[13];
#pragma unroll
        for (int k = 0; k < 13; k++) { V[k][0] = tap[2 * k]; V[k][1] = tap[2 * k + 1]; }
#pragma unroll
        for (int e = 0; e < 8; e++) {
            const float* we = w1 + e * 27;
            f2v a2; a2[0] = b1[e]; a2[1] = 0.f;
#pragma unroll
            for (int k = 0; k < 13; k++) {
                f2v ww; ww[0] = we[2 * k]; ww[1] = we[2 * k + 1];
                a2 = __builtin_elementwise_fma(V[k], ww, a2);
            }
            float acc = a2[0] + a2[1] + tap[26] * we[26];
            s2[e] = 256.0f * __builtin_amdgcn_rcpf(1.0f + EXP2F(acc * NLOG2E));
        }
    };
    float s0[8], s1[8];
    conv8(tap0, s0);
    conv8(tap1, s1);

    const float k511 = 256.0f / 511.0f;
    float fxb = fmaf((float)i, k511, 255.5f);   // feeds gx (reference axis swap)
    float fy0 = fmaf((float)j0, k511, 255.5f);
    float fy1 = fy0 + k511;

    // ---- gather phase 1: quad entry addresses + fp32 weights ----
    int   adrA[5], adrB[5];
    float wXA[5][2], wYA[5][2], wXB[5][2], wYB[5][2];
    auto phase1 = [&](const float* s2, float fyb, int (&adr)[5],
                      float (&wX)[5][2], float (&wY)[5][2]) {
#pragma unroll
        for (int q = 0; q < 5; q++) {
            float ixf = (q < 4) ? (fxb + s2[2 * q])     : fxb;
            float iyf = (q < 4) ? (fyb + s2[2 * q + 1]) : fyb;
            int ix0 = (int)ixf, iy0 = (int)iyf;         // positive: trunc == floor; >= 255
            float wx1 = ixf - (float)ix0, wy1 = iyf - (float)iy0;
            wX[q][0] = (ix0 <= 511) ? (1.f - wx1) : 0.f;
            wX[q][1] = (ix0 <= 510) ? wx1 : 0.f;
            wY[q][0] = (iy0 <= 511) ? (1.f - wy1) : 0.f;
            wY[q][1] = (iy0 <= 510) ? wy1 : 0.f;
            int x0c = min(ix0, 511), y0c = min(iy0, 511);
            int P  = ((y0c & 1) << 1) | (x0c & 1);
            int Qx = (x0c >> 1) - 127;                  // 0..128
            int Qy = (y0c >> 1) - 127;
            adr[q] = (P * QPAIRS + Qy * QN + Qx) << 3;
        }
    };

    // ---- gather phase 2: 10 single 8-B loads, all in flight ----
    phase1(s0, fy0, adrA, wXA, wYA);
    HPair pA[5];
#pragma unroll
    for (int q = 0; q < 5; q++)
        pA[q] = *(const HPair*)(hb + (size_t)(q * QPLANE + adrA[q]));
    phase1(s1, fy1, adrB, wXB, wYB);   // VALU overlaps px0 loads
    HPair pB[5];
#pragma unroll
    for (int q = 0; q < 5; q++)
        pB[q] = *(const HPair*)(hb + (size_t)(q * QPLANE + adrB[q]));
    __builtin_amdgcn_sched_barrier(0);   // pin all 10 gathers in flight before any use

    // ---- gather phase 3: fp32 bilinear on pre-dotted scalars ----
    float ogA[3] = {0.f, 0.f, 0.f}, ogB[3] = {0.f, 0.f, 0.f};
    auto phase3 = [&](HPair (&pv)[5], float (&wX)[5][2], float (&wY)[5][2], float* og) {
#pragma unroll
        for (int q = 0; q < 5; q++) {
            int g = q / 3;              // 0,0,0,1,1
            float v00 = (float)pv[q].lo[0], v01 = (float)pv[q].lo[1];
            float v10 = (float)pv[q].hi[0], v11c = (float)pv[q].hi[1];
            float r0 = fmaf(v01,  wX[q][1], v00 * wX[q][0]);
            float r1 = fmaf(v11c, wX[q][1], v10 * wX[q][0]);
            og[g] = fmaf(r1, wY[q][1], fmaf(r0, wY[q][0], og[g]));
        }
    };
    phase3(pA, wXA, wYA, ogA);
    phase3(pB, wXB, wYB, ogB);

    // ---- mirror points p=5..8: only pixel (0,0) of each image contributes ----
    if ((i | j0) == 0) {
#pragma unroll
        for (int p = 5; p < 9; p++) {
            float ixf = fxb + 512.0f - s0[2 * (p - 5)];
            float iyf = fy0 + 512.0f - s0[2 * (p - 5) + 1];
            float ix0f = floorf(ixf), iy0f = floorf(iyf);
            float wx1 = ixf - ix0f, wy1 = iyf - iy0f;
            float wx0 = 1.f - wx1,  wy0 = 1.f - wy1;
            int ix0 = (int)ix0f, iy0 = (int)iy0f;
            float t0 = 0.f, t1 = 0.f, t2 = 0.f;
            for (int cy = 0; cy < 2; cy++) {
                int yc2 = iy0 + cy;
                if (yc2 < 0 || yc2 >= HDIM) continue;
                float wy = cy ? wy1 : wy0;
                for (int cx = 0; cx < 2; cx++) {
                    int xcc2 = ix0 + cx;
                    if (xcc2 < 0 || xcc2 >= WDIM) continue;
                    float wgt = wy * (cx ? wx1 : wx0);
                    int base = (yc2 << 9) + xcc2;
                    t0 = fmaf(xb[base],             wgt, t0);
                    t1 = fmaf(xb[PLANE + base],     wgt, t1);
                    t2 = fmaf(xb[2 * PLANE + base], wgt, t2);
                }
            }
            int g  = p / 3;
            int k0 = (p % 3) * 3;
            ogA[g] = fmaf(t0, w2[g * 9 + k0 + 0], ogA[g]);
            ogA[g] = fmaf(t1, w2[g * 9 + k0 + 1], ogA[g]);
            ogA[g] = fmaf(t2, w2[g * 9 + k0 + 2], ogA[g]);
        }
    }

    // ---- bias + relu + paired store ----
    size_t ob = (size_t)(b * 3) * PLANE + ((size_t)i << 9) + j0;
#pragma unroll
    for (int g = 0; g < 3; g++) {
        float u0 = ogA[g] + b2[g];
        float u1 = ogB[g] + b2[g];
        f2v st;
        st[0] = u0 > 0.f ? u0 : 0.f;
        st[1] = u1 > 0.f ? u1 : 0.f;
        *(f2v*)(out + ob + (size_t)g * PLANE) = st;
    }
}

// ================= tier-2: v11 path (x-pair fp16 texel pack) =================
__global__ __launch_bounds__(256) void repack_tiles(
    const float* __restrict__ x, char* __restrict__ xp)
{
    int b    = blockIdx.x & 7;
    int rest = blockIdx.x >> 3;
    int p    = rest & 1;
    int Qc   = rest >> 1;
    int xb0  = 254 + 2 * Qc + p;
    int x1   = xb0 + 1;
    bool x1v = (x1 < 512);

    const float* xb = x + (size_t)b * 3 * PLANE;
    char* dst = xp + (size_t)b * IMGSTRIDE + (size_t)p * PARSTRIDE
                   + (size_t)Qc * QSTRIDE;

    for (int t = threadIdx.x; t < YROWS; t += 256) {
        int y = YROW0 + t;
        half8v o;
        if (y < 512) {
            int base = (y << 9) + xb0;
            float a0 = xb[base];
            float a1 = xb[PLANE + base];
            float a2 = xb[2 * PLANE + base];
            float b0 = 0.f, b1c = 0.f, b2c = 0.f;
            if (x1v) {
                b0  = xb[base + 1];
                b1c = xb[PLANE + base + 1];
                b2c = xb[2 * PLANE + base + 1];
            }
            o[0] = (_Float16)a0; o[1] = (_Float16)a1; o[2] = (_Float16)a2; o[3] = (_Float16)0.f;
            o[4] = (_Float16)b0; o[5] = (_Float16)b1c; o[6] = (_Float16)b2c; o[7] = (_Float16)0.f;
        } else {
#pragma unroll
            for (int k = 0; k < 8; k++) o[k] = (_Float16)0.f;
        }
        *(half8v*)(dst + (size_t)t * 16) = o;
    }
}

__global__ __launch_bounds__(256) void seesaw_v11(
    const float* __restrict__ x, const char* __restrict__ xpack,
    const float* __restrict__ w1, const float* __restrict__ b1,
    const float* __restrict__ w2, const float* __restrict__ b2,
    float* __restrict__ out)
{
    int t  = threadIdx.x;
    int b  = blockIdx.x & 7;
    int i  = blockIdx.x >> 3;
    int j0 = t << 1;

    const float* xb = x + (size_t)b * 3 * PLANE;
    const char*  hb = xpack + (size_t)b * IMGSTRIDE;

    int cm = j0 - 1; if (cm < 0) cm = 0;
    int cp = j0 + 2; if (cp > 511) cp = 511;
    bool jlo = (t == 0), jhi = (t == 255);

    float vm[9], va[9], vb9[9], vp9[9];
    if (i >= 1 && i <= 510) {
#pragma unroll
        for (int di = 0; di < 3; di++) {
            const float* row = xb + ((i + di - 1) << 9);
#pragma unroll
            for (int c = 0; c < 3; c++) {
                const float* rc = row + c * PLANE;
                float m = rc[cm]; if (jlo) m = 0.f;
                f2v  mid = *(const f2v*)(rc + j0);
                float pv = rc[cp]; if (jhi) pv = 0.f;
                int r = c * 3 + di;
                vm[r] = m; va[r] = mid[0]; vb9[r] = mid[1]; vp9[r] = pv;
            }
        }
    } else {
#pragma unroll
        for (int di = 0; di < 3; di++) {
            int y = i + di - 1;
            bool yv = (unsigned)y < (unsigned)HDIM;
            const float* row = xb + ((yv ? y : 0) << 9);
#pragma unroll
            for (int c = 0; c < 3; c++) {
                const float* rc = row + c * PLANE;
                float m = rc[cm]; if (jlo || !yv) m = 0.f;
                f2v  mid = *(const f2v*)(rc + j0);
                float pv = rc[cp]; if (jhi || !yv) pv = 0.f;
                float m0 = yv ? mid[0] : 0.f;
                float m1 = yv ? mid[1] : 0.f;
                int r = c * 3 + di;
                vm[r] = m; va[r] = m0; vb9[r] = m1; vp9[r] = pv;
            }
        }
    }
    __builtin_amdgcn_sched_barrier(0);

    float tap0[27], tap1[27];
#pragma unroll
    for (int c = 0; c < 3; c++)
#pragma unroll
        for (int di = 0; di < 3; di++) {
            int r = c * 3 + di, k = c * 9 + di * 3;
            tap0[k]     = vm[r];  tap0[k + 1] = va[r];  tap0[k + 2] = vb9[r];
            tap1[k]     = va[r];  tap1[k + 1] = vb9[r]; tap1[k + 2] = vp9[r];
        }

    const float NLOG2E = -1.44269504f;
    auto conv8 = [&](const float* tap, float* s2) {
        f2v V[13];
#pragma unroll
        for (int k = 0; k < 13; k++) { V[k][0] = tap[2 * k]; V[k][1] = tap[2 * k + 1]; }
#pragma unroll
        for (int e = 0; e < 8; e++) {
            const float* we = w1 + e * 27;
            f2v a2; a2[0] = b1[e]; a2[1] = 0.f;
#pragma unroll
            for (int k = 0; k < 13; k++) {
                f2v ww; ww[0] = we[2 * k]; ww[1] = we[2 * k + 1];
                a2 = __builtin_elementwise_fma(V[k], ww, a2);
            }
            float acc = a2[0] + a2[1] + tap[26] * we[26];
            s2[e] = 256.0f * __builtin_amdgcn_rcpf(1.0f + EXP2F(acc * NLOG2E));
        }
    };
    float s0[8], s1[8];
    conv8(tap0, s0);
    conv8(tap1, s1);

    half2v w2a[5], w2b[5];
#pragma unroll
    for (int q = 0; q < 5; q++) {
        w2a[q][0] = (_Float16)w2[q * 3];
        w2a[q][1] = (_Float16)w2[q * 3 + 1];
        w2b[q][0] = (_Float16)w2[q * 3 + 2];
        w2b[q][1] = (_Float16)0.f;
    }

    const float k511 = 256.0f / 511.0f;
    float fxb = fmaf((float)i, k511, 255.5f);
    float fy0 = fmaf((float)j0, k511, 255.5f);
    float fy1 = fy0 + k511;

    int   adrA[5], adrB[5];
    float wXA[5][2], wYA[5][2], wXB[5][2], wYB[5][2];
    auto phase1 = [&](const float* s2, float fyb, int (&adr)[5],
                      float (&wX)[5][2], float (&wY)[5][2]) {
#pragma unroll
        for (int q = 0; q < 5; q++) {
            float ixf = (q < 4) ? (fxb + s2[2 * q])     : fxb;
            float iyf = (q < 4) ? (fyb + s2[2 * q + 1]) : fyb;
            int ix0 = (int)ixf, iy0 = (int)iyf;
            float wx1 = ixf - (float)ix0, wy1 = iyf - (float)iy0;
            wX[q][0] = (ix0 <= 511) ? (1.f - wx1) : 0.f;
            wX[q][1] = (ix0 <= 510) ? wx1 : 0.f;
            wY[q][0] = (iy0 <= 511) ? (1.f - wy1) : 0.f;
            wY[q][1] = (iy0 <= 510) ? wy1 : 0.f;
            int x0c = min(ix0, 511);
            int y0c = min(iy0, 511);
            int Qc  = (x0c >> 1) - 127;
            int off = (Qc << 12) + (Qc << 6) + ((y0c - 254) << 4);
            adr[q] = off + ((x0c & 1) ? PARSTRIDE : 0);
        }
    };

    phase1(s0, fy0, adrA, wXA, wYA);
    HQuad qA[5][2];
#pragma unroll
    for (int q = 0; q < 5; q++) {
        qA[q][0] = *(const HQuad*)(hb + (size_t)adrA[q]);
        qA[q][1] = *(const HQuad*)(hb + (size_t)adrA[q] + 16);
    }
    phase1(s1, fy1, adrB, wXB, wYB);
    HQuad qB[5][2];
#pragma unroll
    for (int q = 0; q < 5; q++) {
        qB[q][0] = *(const HQuad*)(hb + (size_t)adrB[q]);
        qB[q][1] = *(const HQuad*)(hb + (size_t)adrB[q] + 16);
    }
    __builtin_amdgcn_sched_barrier(0);

    float ogA[3] = {0.f, 0.f, 0.f}, ogB[3] = {0.f, 0.f, 0.f};
    auto phase3 = [&](HQuad (&qv)[5][2], float (&wX)[5][2], float (&wY)[5][2], float* og) {
#pragma unroll
        for (int q = 0; q < 5; q++) {
            int g = q / 3;
            float dl0 = FDOT2(qv[q][0].p0, w2a[q], FDOT2(qv[q][0].p1, w2b[q], 0.f));
            float dh0 = FDOT2(qv[q][0].p2, w2a[q], FDOT2(qv[q][0].p3, w2b[q], 0.f));
            float dl1 = FDOT2(qv[q][1].p0, w2a[q], FDOT2(qv[q][1].p1, w2b[q], 0.f));
            float dh1 = FDOT2(qv[q][1].p2, w2a[q], FDOT2(qv[q][1].p3, w2b[q], 0.f));
            float r0 = fmaf(dh0, wX[q][1], dl0 * wX[q][0]);
            float r1 = fmaf(dh1, wX[q][1], dl1 * wX[q][0]);
            og[g] = fmaf(r1, wY[q][1], fmaf(r0, wY[q][0], og[g]));
        }
    };
    phase3(qA, wXA, wYA, ogA);
    phase3(qB, wXB, wYB, ogB);

    if ((i | j0) == 0) {
#pragma unroll
        for (int p = 5; p < 9; p++) {
            float ixf = fxb + 512.0f - s0[2 * (p - 5)];
            float iyf = fy0 + 512.0f - s0[2 * (p - 5) + 1];
            float ix0f = floorf(ixf), iy0f = floorf(iyf);
            float wx1 = ixf - ix0f, wy1 = iyf - iy0f;
            float wx0 = 1.f - wx1,  wy0 = 1.f - wy1;
            int ix0 = (int)ix0f, iy0 = (int)iy0f;
            float t0 = 0.f, t1 = 0.f, t2 = 0.f;
            for (int cy = 0; cy < 2; cy++) {
                int yc2 = iy0 + cy;
                if (yc2 < 0 || yc2 >= HDIM) continue;
                float wy = cy ? wy1 : wy0;
                for (int cx = 0; cx < 2; cx++) {
                    int xcc2 = ix0 + cx;
                    if (xcc2 < 0 || xcc2 >= WDIM) continue;
                    float wgt = wy * (cx ? wx1 : wx0);
                    int base = (yc2 << 9) + xcc2;
                    t0 = fmaf(xb[base],             wgt, t0);
                    t1 = fmaf(xb[PLANE + base],     wgt, t1);
                    t2 = fmaf(xb[2 * PLANE + base], wgt, t2);
                }
            }
            int g  = p / 3;
            int k0 = (p % 3) * 3;
            ogA[g] = fmaf(t0, w2[g * 9 + k0 + 0], ogA[g]);
            ogA[g] = fmaf(t1, w2[g * 9 + k0 + 1], ogA[g]);
            ogA[g] = fmaf(t2, w2[g * 9 + k0 + 2], ogA[g]);
        }
    }

    size_t ob = (size_t)(b * 3) * PLANE + ((size_t)i << 9) + j0;
#pragma unroll
    for (int g = 0; g < 3; g++) {
        float u0 = ogA[g] + b2[g];
        float u1 = ogB[g] + b2[g];
        f2v st;
        st[0] = u0 > 0.f ? u0 : 0.f;
        st[1] = u1 > 0.f ? u1 : 0.f;
        *(f2v*)(out + ob + (size_t)g * PLANE) = st;
    }
}

// ================= tier-3: no-workspace fallback =================
__global__ __launch_bounds__(256) void seesaw_fused_v1(
    const float* __restrict__ x, const float* __restrict__ w1,
    const float* __restrict__ b1, const float* __restrict__ w2,
    const float* __restrict__ b2, float* __restrict__ out)
{
    int t = threadIdx.x;
    int gid = blockIdx.x * 256 + t;
    int j = gid & (WDIM - 1);
    int i = (gid >> 9) & (HDIM - 1);
    int b = gid >> 18;
    const float* xb = x + (size_t)b * 3 * PLANE;
    float acc[8];
#pragma unroll
    for (int e = 0; e < 8; e++) acc[e] = b1[e];
#pragma unroll
    for (int di = 0; di < 3; di++) {
        int y = i + di - 1;
        if (y < 0 || y >= HDIM) continue;
#pragma unroll
        for (int dj = 0; dj < 3; dj++) {
            int xc = j + dj - 1;
            if (xc < 0 || xc >= WDIM) continue;
            size_t base = (size_t)y * WDIM + xc;
#pragma unroll
            for (int c = 0; c < 3; c++) {
                float v = xb[(size_t)c * PLANE + base];
#pragma unroll
                for (int e = 0; e < 8; e++)
                    acc[e] = fmaf(v, w1[e * 27 + c * 9 + di * 3 + dj], acc[e]);
            }
        }
    }
    float s[8];
#pragma unroll
    for (int e = 0; e < 8; e++) s[e] = 1.0f / (1.0f + __expf(-acc[e]));
    const float inv511 = 1.0f / 511.0f;
    float bx = (float)i * inv511, by = (float)j * inv511;
    float og0 = 0.f, og1 = 0.f, og2 = 0.f;
#pragma unroll
    for (int p = 0; p < 9; p++) {
        float c0, c1;
        if (p < 4)       { c0 = s[2 * p];              c1 = s[2 * p + 1]; }
        else if (p == 4) { c0 = 0.f;                   c1 = 0.f; }
        else             { c0 = 2.0f - s[2 * (p - 5)]; c1 = 2.0f - s[2 * (p - 5) + 1]; }
        float ixf = (bx + c0) * 256.0f + 255.5f;
        float iyf = (by + c1) * 256.0f + 255.5f;
        float ix0f = floorf(ixf), iy0f = floorf(iyf);
        float wx1 = ixf - ix0f, wy1 = iyf - iy0f;
        float wx0 = 1.f - wx1,  wy0 = 1.f - wy1;
        int ix0 = (int)ix0f, iy0 = (int)iy0f;
        float s0 = 0.f, s1 = 0.f, s2 = 0.f;
#pragma unroll
        for (int cy = 0; cy < 2; cy++) {
            int yc = iy0 + cy;
            if (yc < 0 || yc >= HDIM) continue;
            float wy = cy ? wy1 : wy0;
#pragma unroll
            for (int cx = 0; cx < 2; cx++) {
                int xcc = ix0 + cx;
                if (xcc < 0 || xcc >= WDIM) continue;
                float wgt = wy * (cx ? wx1 : wx0);
                size_t base = (size_t)yc * WDIM + xcc;
                s0 = fmaf(xb[base],             wgt, s0);
                s1 = fmaf(xb[PLANE + base],     wgt, s1);
                s2 = fmaf(xb[2 * PLANE + base], wgt, s2);
            }
        }
        int g  = p / 3;
        int k0 = (p % 3) * 3;
        float* og = (g == 0) ? &og0 : (g == 1) ? &og1 : &og2;
        *og = fmaf(s0, w2[g * 9 + k0 + 0], *og);
        *og = fmaf(s1, w2[g * 9 + k0 + 1], *og);
        *og = fmaf(s2, w2[g * 9 + k0 + 2], *og);
    }
    size_t ob = (size_t)(b * 3) * PLANE + (size_t)i * WDIM + j;
    float v0 = og0 + b2[0], v1 = og1 + b2[1], v2 = og2 + b2[2];
    out[ob]             = v0 > 0.f ? v0 : 0.f;
    out[ob + PLANE]     = v1 > 0.f ? v1 : 0.f;
    out[ob + 2 * PLANE] = v2 > 0.f ? v2 : 0.f;
}

extern "C" void kernel_launch(void* const* d_in, const int* in_sizes, int n_in,
                              void* d_out, int out_size, void* d_ws, size_t ws_size,
                              hipStream_t stream) {
    const float* x  = (const float*)d_in[0];
    const float* w1 = (const float*)d_in[1];
    const float* b1 = (const float*)d_in[2];
    const float* w2 = (const float*)d_in[3];
    const float* b2 = (const float*)d_in[4];
    float* out = (float*)d_out;

    int total = BATCH * HDIM * WDIM;                    // 2,097,152
    size_t need12 = (size_t)BATCH * IMG12 + 64;         // ~20.3 MiB pre-dotted quad packs
    size_t need11 = (size_t)BATCH * IMGSTRIDE + 16;     // ~8.2 MiB parity tile packs

    if (ws_size >= need12) {
        repack_dots<<<8 * 4 * QN, 256, 0, stream>>>(x, w2, (char*)d_ws);
        seesaw_v12<<<BATCH * HDIM, 256, 0, stream>>>(x, (const char*)d_ws,
                                                     w1, b1, w2, b2, out);
    } else if (ws_size >= need11) {
        repack_tiles<<<8 * 2 * QC_N, 256, 0, stream>>>(x, (char*)d_ws);
        seesaw_v11<<<BATCH * HDIM, 256, 0, stream>>>(x, (const char*)d_ws,
                                                     w1, b1, w2, b2, out);
    } else {
        seesaw_fused_v1<<<total / 256, 256, 0, stream>>>(x, w1, b1, w2, b2, out);
    }
}